// Round 5
// baseline (130.056 us; speedup 1.0000x reference)
//
#include <hip/hip_runtime.h>
#include <math.h>
#include <stdint.h>

// Problem constants (match reference)
constexpr int kVerts = 5000;
constexpr int kFaces = 10000;
constexpr int kPts   = 16384;   // BATCH * N_PTS = 2 * 8192
constexpr int kOuter = 4;
constexpr int kInner = 50;

#define SCALE 10.0f

// KNN structure: 4 points per lane, 16 waves per block, 4 face quarters.
// Grid = 64 point-groups x 4 quarters = 256 blocks (1 block/CU, 16 waves).
// Quarter is staged into LDS as SoA in 2 chunks of 1250 faces.
#define KNN_WAVES 16
#define KNN_FQ    4
constexpr int kQuarter     = kFaces / KNN_FQ;        // 2500
constexpr int kChunk       = kQuarter / 2;           // 1250 (even)
constexpr int kPtsPerLane  = 4;
constexpr int kPtsPerBlock = 64 * kPtsPerLane;       // 256
constexpr int kPtGroups    = kPts / kPtsPerBlock;    // 64

typedef float v2f __attribute__((ext_vector_type(2)));

// VOP3P packed f32: per-half IEEE identical to v_mul_f32 / v_add_f32.
__device__ __forceinline__ v2f pk_mul(v2f a, v2f b) {
    v2f d; asm("v_pk_mul_f32 %0, %1, %2" : "=v"(d) : "v"(a), "v"(b)); return d;
}
__device__ __forceinline__ v2f pk_add(v2f a, v2f b) {
    v2f d; asm("v_pk_add_f32 %0, %1, %2" : "=v"(d) : "v"(a), "v"(b)); return d;
}

// ---------------------------------------------------------------------------
// Adam bias-correction table (same constexpr values as all prior rounds).
// ---------------------------------------------------------------------------
struct BiasTabP { float rb[kInner + 2][2]; };
constexpr BiasTabP make_tabp() {
    BiasTabP t{};
    float b1 = 1.0f, b2 = 1.0f;
    for (int i = 0; i < kInner; ++i) {
        b1 *= 0.9f; b2 *= 0.999f;
        t.rb[i][0] = 1.0f / (1.0f - b1);
        t.rb[i][1] = 1.0f / (1.0f - b2);
    }
    t.rb[kInner][0]     = t.rb[kInner - 1][0];
    t.rb[kInner][1]     = t.rb[kInner - 1][1];
    t.rb[kInner + 1][0] = t.rb[kInner - 1][0];
    t.rb[kInner + 1][1] = t.rb[kInner - 1][1];
    return t;
}
constexpr BiasTabP kTabP = make_tabp();

// ---------------------------------------------------------------------------
// Kernel 0: triangle centers, SoA output (cx | cy | cz | cc arrays), same
// bit-identical *_rn formulas as every prior round.
// ---------------------------------------------------------------------------
__global__ __launch_bounds__(256)
void centers_kernel(const float* __restrict__ mesh_V,
                    const int*   __restrict__ mesh_F,
                    float*       __restrict__ soa)   // [4][kFaces]
{
    const int f = blockIdx.x * 256 + threadIdx.x;
    if (f >= kFaces) return;
    const int i0 = mesh_F[f * 3 + 0];
    const int i1 = mesh_F[f * 3 + 1];
    const int i2 = mesh_F[f * 3 + 2];
    const float cx = __fdiv_rn(__fadd_rn(__fadd_rn(mesh_V[i0*3+0], mesh_V[i1*3+0]), mesh_V[i2*3+0]), 3.0f);
    const float cy = __fdiv_rn(__fadd_rn(__fadd_rn(mesh_V[i0*3+1], mesh_V[i1*3+1]), mesh_V[i2*3+1]), 3.0f);
    const float cz = __fdiv_rn(__fadd_rn(__fadd_rn(mesh_V[i0*3+2], mesh_V[i1*3+2]), mesh_V[i2*3+2]), 3.0f);
    const float cc = __fadd_rn(__fadd_rn(__fmul_rn(cx, cx), __fmul_rn(cy, cy)),
                               __fmul_rn(cz, cz));
    soa[0 * kFaces + f] = cx;
    soa[1 * kFaces + f] = cy;
    soa[2 * kFaces + f] = cz;
    soa[3 * kFaces + f] = cc;
}

// ---------------------------------------------------------------------------
// Kernel 1: KNN (K=1).
// Round-9: at 2 blocks/CU the LDS pipe (5000 broadcast b128 x ~12cyc =
// ~25us/CU) exceeded the 20.8us VALU floor. Changes:
//  (a) 4 pts/lane -> 1 block/CU -> 2500 reads/CU (~12.5us LDS)
//  (b) SoA centers + packed v_pk_mul/add_f32: ds_read_b64 = a face PAIR,
//      per-half op sequence identical to the scalar chain. Pre-negated
//      doubled query makes d2 = (q2+cw) + (-dot2) with NO modifiers:
//      (-a)*b = -(a*b), (-u)+(-v) = -(u+v), x-y = x+(-y) -- all exact.
//      Eval cost 10 -> 6.5 insts/face/pt (VALU floor ~13.5us).
// Tie semantics: even faces -> acc0, odd -> acc1; every merge (acc pair,
// cross-wave, cross-quarter in solve) is lexicographic (d2, f) => global
// first-occurrence argmin, same fidx as prior rounds.
// Slice boundaries forced EVEN so all v2f LDS accesses are 8B-aligned.
// LDS: 4*1250*4 (SoA chunk) + 16*256*8 (merge) = 52768 B.
// ---------------------------------------------------------------------------
__global__ __launch_bounds__(1024)
void knn_kernel(const float* __restrict__ verts,
                const float* __restrict__ soa,      // [4][kFaces]
                float*       __restrict__ ws_d2,    // [KNN_FQ][kPts]
                int*         __restrict__ ws_f)     // [KNN_FQ][kPts]
{
    __shared__ float s_soa[4][kChunk];                     // 20000 B
    __shared__ float s_best [KNN_WAVES][kPtsPerBlock];     // 16384 B
    __shared__ int   s_bestf[KNN_WAVES][kPtsPerBlock];     // 16384 B

    const int tid  = threadIdx.x;
    const int lane = tid & 63;
    const int wv   = __builtin_amdgcn_readfirstlane(tid >> 6);   // 0..15
    const int pg   = blockIdx.x >> 2;   // point group 0..63
    const int fq   = blockIdx.x & 3;    // face quarter 0..3
    const int qbeg = fq * kQuarter;

    // ---- per-lane 4 points: pre-negated doubled coords (exact) + |q|^2 ----
    v2f ndx[kPtsPerLane], ndy[kPtsPerLane], ndz[kPtsPerLane], q2p[kPtsPerLane];
#pragma unroll
    for (int k = 0; k < kPtsPerLane; ++k) {
        const int p = pg * kPtsPerBlock + k * 64 + lane;
        const float qx = verts[p * 3 + 0];
        const float qy = verts[p * 3 + 1];
        const float qz = verts[p * 3 + 2];
        const float q2 = __fadd_rn(__fadd_rn(__fmul_rn(qx, qx), __fmul_rn(qy, qy)),
                                   __fmul_rn(qz, qz));
        const float nx = -__fmul_rn(2.0f, qx);
        const float ny = -__fmul_rn(2.0f, qy);
        const float nz = -__fmul_rn(2.0f, qz);
        ndx[k] = (v2f){nx, nx};
        ndy[k] = (v2f){ny, ny};
        ndz[k] = (v2f){nz, nz};
        q2p[k] = (v2f){q2, q2};
    }

    float bd0[kPtsPerLane], bd1[kPtsPerLane];
    int   bf0[kPtsPerLane], bf1[kPtsPerLane];
#pragma unroll
    for (int k = 0; k < kPtsPerLane; ++k) {
        bd0[k] = INFINITY;   bd1[k] = INFINITY;
        bf0[k] = 0x7fffffff; bf1[k] = 0x7fffffff;
    }

    // even-aligned, even-sized wave slices covering [0, kChunk)
    const int fbeg = 2 * ((wv * (kChunk / 2)) / KNN_WAVES);
    const int fend = 2 * (((wv + 1) * (kChunk / 2)) / KNN_WAVES);

    for (int c = 0; c < 2; ++c) {
        const int cbase = qbeg + c * kChunk;   // global face base of chunk

        // ---- stage chunk as SoA via coalesced v2f loads/stores ----
        for (int o = tid; o < 4 * (kChunk / 2); o += 1024) {
            const int comp = o / (kChunk / 2);
            const int idx  = o - comp * (kChunk / 2);
            const v2f val = *reinterpret_cast<const v2f*>(soa + comp * kFaces + cbase + 2 * idx);
            *reinterpret_cast<v2f*>(&s_soa[comp][2 * idx]) = val;
        }
        __syncthreads();

        // ---- packed scan: face pair per iteration, wave-uniform b64 reads ----
#pragma unroll 2
        for (int f = fbeg; f < fend; f += 2) {
            const v2f cx2 = *reinterpret_cast<const v2f*>(&s_soa[0][f]);
            const v2f cy2 = *reinterpret_cast<const v2f*>(&s_soa[1][f]);
            const v2f cz2 = *reinterpret_cast<const v2f*>(&s_soa[2][f]);
            const v2f cw2 = *reinterpret_cast<const v2f*>(&s_soa[3][f]);
            const int gf  = cbase + f;
#pragma unroll
            for (int k = 0; k < kPtsPerLane; ++k) {
                const v2f m0   = pk_mul(ndx[k], cx2);
                const v2f m1   = pk_mul(ndy[k], cy2);
                const v2f m2   = pk_mul(ndz[k], cz2);
                const v2f s01  = pk_add(m0, m1);
                const v2f dotn = pk_add(s01, m2);        // = -dot2, exact
                const v2f qc   = pk_add(q2p[k], cw2);    // q2 + |c|^2
                const v2f d2   = pk_add(qc, dotn);       // == (q2+cw) - dot2
                if (d2.x < bd0[k]) { bd0[k] = d2.x; bf0[k] = gf; }
                if (d2.y < bd1[k]) { bd1[k] = d2.y; bf1[k] = gf + 1; }
            }
        }
        __syncthreads();   // before next chunk's stage overwrites s_soa
    }

    // per-point lexicographic merge of the 2 accumulators (smaller f on ties)
#pragma unroll
    for (int k = 0; k < kPtsPerLane; ++k) {
        if (bd1[k] < bd0[k] || (bd1[k] == bd0[k] && bf1[k] < bf0[k])) {
            bd0[k] = bd1[k]; bf0[k] = bf1[k];
        }
        s_best [wv][k * 64 + lane] = bd0[k];
        s_bestf[wv][k * 64 + lane] = bf0[k];
    }
    __syncthreads();

    // cross-wave merge: fully lexicographic (wave face-sets interleave
    // across chunks, so the index tiebreak is required for first-occurrence)
    if (tid < kPtsPerBlock) {
        float best  = s_best [0][tid];
        int   bestf = s_bestf[0][tid];
#pragma unroll
        for (int w = 1; w < KNN_WAVES; ++w) {
            const float ob = s_best [w][tid];
            const int   of = s_bestf[w][tid];
            if (ob < best || (ob == best && of < bestf)) { best = ob; bestf = of; }
        }
        const int p = pg * kPtsPerBlock + tid;
        ws_d2[fq * kPts + p] = best;
        ws_f [fq * kPts + p] = bestf;
    }
}

// ---------------------------------------------------------------------------
// quad_perm DPP broadcast: all lanes of each 4-lane quad read lane K.
// ---------------------------------------------------------------------------
template<int K>
__device__ __forceinline__ float qbcast(float v) {
    return __int_as_float(__builtin_amdgcn_update_dpp(
        0, __float_as_int(v), K * 0x55 /*quad_perm[K,K,K,K]*/, 0xF, 0xF, true));
}

// ---------------------------------------------------------------------------
// Kernel 2: solve — UNCHANGED from round 4 (4 lanes per point, one Adam
// channel per lane, DPP quad broadcasts).
// ---------------------------------------------------------------------------
__global__ __launch_bounds__(256)
void solve_kernel(const float* __restrict__ verts,
                  const float* __restrict__ mesh_V,
                  const float* __restrict__ mesh_N,
                  const int*   __restrict__ mesh_F,
                  const float* __restrict__ ws_d2,
                  const int*   __restrict__ ws_f,
                  float*       __restrict__ out)
{
    const int t  = blockIdx.x * 256 + threadIdx.x;
    const int p  = t >> 2;          // point index
    const int ch = t & 3;           // 0=u, 1=v, 2=d, 3=d-duplicate
    const bool isV = (ch == 1);
    const bool isD = (ch >= 2);

    // merge quarters: strict < keeps the earlier quarter on exact ties
    float bdm = ws_d2[p];
    int   f   = ws_f[p];
#pragma unroll
    for (int q = 1; q < KNN_FQ; ++q) {
        const float d  = ws_d2[q * kPts + p];
        const int   ff = ws_f [q * kPts + p];
        if (d < bdm) { bdm = d; f = ff; }
    }
    if (ch == 0) out[p] = (float)f;   // fidx as float (exact for idx < 2^24)

    const float qx = verts[p * 3 + 0];
    const float qy = verts[p * 3 + 1];
    const float qz = verts[p * 3 + 2];

    const int i0 = mesh_F[f * 3 + 0];
    const int i1 = mesh_F[f * 3 + 1];
    const int i2 = mesh_F[f * 3 + 2];

    const float V0x = mesh_V[i0*3+0], V0y = mesh_V[i0*3+1], V0z = mesh_V[i0*3+2];
    const float V1x = mesh_V[i1*3+0], V1y = mesh_V[i1*3+1], V1z = mesh_V[i1*3+2];
    const float V2x = mesh_V[i2*3+0], V2y = mesh_V[i2*3+1], V2z = mesh_V[i2*3+2];
    const float N0x = mesh_N[i0*3+0], N0y = mesh_N[i0*3+1], N0z = mesh_N[i0*3+2];
    const float N1x = mesh_N[i1*3+0], N1y = mesh_N[i1*3+1], N1z = mesh_N[i1*3+2];
    const float N2x = mesh_N[i2*3+0], N2y = mesh_N[i2*3+1], N2z = mesh_N[i2*3+2];

    // edge vectors (same formulas as before)
    const float E0x = V0x - V2x, E0y = V0y - V2y, E0z = V0z - V2z;
    const float E1x = V1x - V2x, E1y = V1y - V2y, E1z = V1z - V2z;
    const float F0x = N0x - N2x, F0y = N0y - N2y, F0z = N0z - N2z;
    const float F1x = N1x - N2x, F1y = N1y - N2y, F1z = N1z - N2z;

    // per-lane operand selects (loop-invariant parts)
    const float Aux = isV ? E1x : E0x;   // A when !isD (the isD case is nh, per-iter)
    const float Auy = isV ? E1y : E0y;
    const float Auz = isV ? E1z : E0z;
    const float Bx  = isD ? 0.0f : (isV ? F1x : F0x);
    const float By  = isD ? 0.0f : (isV ? F1y : F0y);
    const float Bz  = isD ? 0.0f : (isV ? F1z : F0z);

    const float tx = qx * SCALE, ty = qy * SCALE, tz = qz * SCALE;
    const float GS = 2.0f / (3.0f * 16384.0f);
    const float B1c = 0.9f,  ONE_M_B1 = 1.0f - 0.9f;
    const float B2c = 0.999f, ONE_M_B2 = 1.0f - 0.999f;

    float vwu = 1.0f / 3.0f, vwv = 1.0f / 3.0f;

#define SOLVE_STEP(RB1, RB2)                                                   \
    {                                                                          \
        const float du = qbcast<0>(dlt);                                       \
        const float dv = qbcast<1>(dlt);                                       \
        const float dd = qbcast<2>(dlt);                                       \
        const float bu = vwu + du;                                             \
        const float bv = vwv + dv;                                             \
        const float bw = (1.0f - bu) - bv;                                     \
        const float cVx = ((bu * V0x + bv * V1x) + bw * V2x) * SCALE;          \
        const float cVy = ((bu * V0y + bv * V1y) + bw * V2y) * SCALE;          \
        const float cVz = ((bu * V0z + bv * V1z) + bw * V2z) * SCALE;          \
        const float nrx = (bu * N0x + bv * N1x) + bw * N2x;                    \
        const float nry = (bu * N0y + bv * N1y) + bw * N2y;                    \
        const float nrz = (bu * N0z + bv * N1z) + bw * N2z;                    \
        const float nn  = (nrx * nrx + nry * nry) + nrz * nrz;                 \
        const float inv = __builtin_amdgcn_rsqf(nn);                           \
        const float nhx = nrx * inv, nhy = nry * inv, nhz = nrz * inv;         \
        const float cNx = nhx * SCALE, cNy = nhy * SCALE, cNz = nhz * SCALE;   \
        const float rx = (cVx + cNx * dd) - tx;                                \
        const float ry = (cVy + cNy * dd) - ty;                                \
        const float rz = (cVz + cNz * dd) - tz;                                \
        const float Ax = isD ? nhx : Aux;                                      \
        const float Ay = isD ? nhy : Auy;                                      \
        const float Az = isD ? nhz : Auz;                                      \
        const float dotA = (rx * Ax + ry * Ay) + rz * Az;                      \
        const float dotB = (rx * Bx + ry * By) + rz * Bz;                      \
        const float nhB  = (nhx * Bx + nhy * By) + nhz * Bz;                   \
        const float nr_r = qbcast<2>(dotA);                                    \
        const float g = GS * (SCALE * dotA + (dd * SCALE) * ((dotB - nr_r * nhB) * inv)); \
        mA = B1c * mA + ONE_M_B1 * g;                                          \
        vA = B2c * vA + ONE_M_B2 * (g * g);                                    \
        const float s = __builtin_amdgcn_rsqf(vA * (RB2) + 1e-16f);            \
        dlt -= 0.01f * (mA * (RB1)) * s;                                       \
    }

    for (int outer = 0; outer < kOuter; ++outer) {
        const float bw0 = (1.0f - vwu) - vwv;
        const float px = ((vwu * V0x + vwv * V1x) + bw0 * V2x);
        const float py = ((vwu * V0y + vwv * V1y) + bw0 * V2y);
        const float pz = ((vwu * V0z + vwv * V1z) + bw0 * V2z);
        const float dx = px - qx, dy = py - qy, dz = pz - qz;
        const float d0 = __builtin_amdgcn_sqrtf((dx * dx + dy * dy) + dz * dz);

        float dlt = isD ? d0 : 0.0f;   // this lane's channel delta
        float mA  = 0.0f, vA = 0.0f;

        float rbA1 = kTabP.rb[0][0], rbA2 = kTabP.rb[0][1];
        float rbB1 = kTabP.rb[1][0], rbB2 = kTabP.rb[1][1];
#pragma unroll 1
        for (int it2 = 0; it2 < kInner / 2; ++it2) {
            const float n1a = kTabP.rb[2 * it2 + 2][0];
            const float n2a = kTabP.rb[2 * it2 + 2][1];
            const float n1b = kTabP.rb[2 * it2 + 3][0];
            const float n2b = kTabP.rb[2 * it2 + 3][1];
            SOLVE_STEP(rbA1, rbA2);
            SOLVE_STEP(rbB1, rbB2);
            rbA1 = n1a; rbA2 = n2a; rbB1 = n1b; rbB2 = n2b;
        }
        vwu += qbcast<0>(dlt);
        vwv += qbcast<1>(dlt);
    }
#undef SOLVE_STEP

    if (ch == 0) {
        out[kPts + 2 * p + 0] = vwu;
        out[kPts + 2 * p + 1] = vwv;
        out[3 * kPts + p]     = 0.0f;   // outlier_mask = False
    }
}

extern "C" void kernel_launch(void* const* d_in, const int* in_sizes, int n_in,
                              void* d_out, int out_size, void* d_ws, size_t ws_size,
                              hipStream_t stream) {
    const float* verts  = (const float*)d_in[0];
    const float* mesh_V = (const float*)d_in[1];
    const float* mesh_N = (const float*)d_in[2];
    const int*   mesh_F = (const int*)d_in[3];
    float* out = (float*)d_out;

    // workspace layout: SoA centers [4][kFaces] | d2 cand [4][kPts] | f cand
    float* ws_soa = (float*)d_ws;                                           // 160000 B
    float* ws_d2  = (float*)((char*)d_ws + 4 * kFaces * sizeof(float));     // KNN_FQ*kPts floats
    int*   ws_f   = (int*)((char*)ws_d2 + KNN_FQ * kPts * sizeof(float));   // KNN_FQ*kPts ints

    hipLaunchKernelGGL(centers_kernel, dim3((kFaces + 255) / 256), dim3(256), 0, stream,
                       mesh_V, mesh_F, ws_soa);
    hipLaunchKernelGGL(knn_kernel,     dim3(kPtGroups * KNN_FQ), dim3(1024), 0, stream,
                       verts, ws_soa, ws_d2, ws_f);
    hipLaunchKernelGGL(solve_kernel,   dim3(kPts * 4 / 256), dim3(256), 0, stream,
                       verts, mesh_V, mesh_N, mesh_F, ws_d2, ws_f, out);
}

// Round 6
// 128.027 us; speedup vs baseline: 1.0159x; 1.0159x over previous
//
#include <hip/hip_runtime.h>
#include <math.h>
#include <stdint.h>

// Problem constants (match reference)
constexpr int kVerts = 5000;
constexpr int kFaces = 10000;
constexpr int kPts   = 16384;   // BATCH * N_PTS = 2 * 8192
constexpr int kOuter = 4;
constexpr int kInner = 50;

#define SCALE 10.0f

// KNN structure: 2 points per lane, 16 waves per block, 4 face quarters.
// Grid = 128 point-groups x 4 quarters = 512 blocks (2 blocks/CU, 32 waves).
// Whole quarter staged once in LDS, pair-interleaved for b128 reads.
#define KNN_WAVES 16
#define KNN_FQ    4
constexpr int kQuarter     = kFaces / KNN_FQ;        // 2500
constexpr int kPairs       = kQuarter / 2;           // 1250
constexpr int kPtsPerLane  = 2;
constexpr int kPtsPerBlock = 64 * kPtsPerLane;       // 128
constexpr int kPtGroups    = kPts / kPtsPerBlock;    // 128

typedef float v2f __attribute__((ext_vector_type(2)));

// VOP3P packed f32: per-half IEEE identical to v_mul_f32 / v_add_f32.
// (Validated round 5: absmax bit-identical to the scalar version.)
__device__ __forceinline__ v2f pk_mul(v2f a, v2f b) {
    v2f d; asm("v_pk_mul_f32 %0, %1, %2" : "=v"(d) : "v"(a), "v"(b)); return d;
}
__device__ __forceinline__ v2f pk_add(v2f a, v2f b) {
    v2f d; asm("v_pk_add_f32 %0, %1, %2" : "=v"(d) : "v"(a), "v"(b)); return d;
}

// ---------------------------------------------------------------------------
// Adam bias-correction table (same constexpr values as all prior rounds).
// ---------------------------------------------------------------------------
struct BiasTabP { float rb[kInner + 2][2]; };
constexpr BiasTabP make_tabp() {
    BiasTabP t{};
    float b1 = 1.0f, b2 = 1.0f;
    for (int i = 0; i < kInner; ++i) {
        b1 *= 0.9f; b2 *= 0.999f;
        t.rb[i][0] = 1.0f / (1.0f - b1);
        t.rb[i][1] = 1.0f / (1.0f - b2);
    }
    t.rb[kInner][0]     = t.rb[kInner - 1][0];
    t.rb[kInner][1]     = t.rb[kInner - 1][1];
    t.rb[kInner + 1][0] = t.rb[kInner - 1][0];
    t.rb[kInner + 1][1] = t.rb[kInner - 1][1];
    return t;
}
constexpr BiasTabP kTabP = make_tabp();

// ---------------------------------------------------------------------------
// Kernel 0: triangle centers, SoA output (cx | cy | cz | cc arrays), same
// bit-identical *_rn formulas as every prior round.
// ---------------------------------------------------------------------------
__global__ __launch_bounds__(256)
void centers_kernel(const float* __restrict__ mesh_V,
                    const int*   __restrict__ mesh_F,
                    float*       __restrict__ soa)   // [4][kFaces]
{
    const int f = blockIdx.x * 256 + threadIdx.x;
    if (f >= kFaces) return;
    const int i0 = mesh_F[f * 3 + 0];
    const int i1 = mesh_F[f * 3 + 1];
    const int i2 = mesh_F[f * 3 + 2];
    const float cx = __fdiv_rn(__fadd_rn(__fadd_rn(mesh_V[i0*3+0], mesh_V[i1*3+0]), mesh_V[i2*3+0]), 3.0f);
    const float cy = __fdiv_rn(__fadd_rn(__fadd_rn(mesh_V[i0*3+1], mesh_V[i1*3+1]), mesh_V[i2*3+1]), 3.0f);
    const float cz = __fdiv_rn(__fadd_rn(__fadd_rn(mesh_V[i0*3+2], mesh_V[i1*3+2]), mesh_V[i2*3+2]), 3.0f);
    const float cc = __fadd_rn(__fadd_rn(__fmul_rn(cx, cx), __fmul_rn(cy, cy)),
                               __fmul_rn(cz, cz));
    soa[0 * kFaces + f] = cx;
    soa[1 * kFaces + f] = cy;
    soa[2 * kFaces + f] = cz;
    soa[3 * kFaces + f] = cc;
}

// ---------------------------------------------------------------------------
// Kernel 1: KNN (K=1).
// Round-10: round-5's pk version was correct (absmax identical) but slow:
// VGPR=36 proves the compiler rematerialized the duplicated-half v2f query
// operands inside the hot loop (needed ~48 live), and 1 block/CU halved
// occupancy. Fixes:
//  (a) 2 pts/lane -> 512 blocks, 2 blocks/CU, 32 waves/CU; live v2f set
//      fits; __launch_bounds__(1024,8) pins the 64-VGPR budget.
//  (b) asm-launder each duplicated v2f pair -> opaque, loop-invariant,
//      cannot be rematerialized.
//  (c) LDS pair-interleaved float4 layout: s_A[p]={cx2,cy2}, s_B[p]=
//      {cz2,cc2} -> 2 ds_read_b128 (one vaddr + offset) per face pair
//      instead of 4 ds_read_b64. ~1.28 MB/CU-pass ~ 6us on the LDS pipe,
//      under the ~14us pk VALU floor.
// Tie semantics unchanged (even->acc0/odd->acc1, all merges lexicographic
// on (d2,f)) -> same fidx as rounds 4/5 -> absmax stays 0.3334961.
// LDS: 20000 (s_A) + 20000 (s_B) + 16384 (merge) = 56384 B; x2 blocks OK.
// ---------------------------------------------------------------------------
__global__ __launch_bounds__(1024, 8)
void knn_kernel(const float* __restrict__ verts,
                const float* __restrict__ soa,      // [4][kFaces]
                float*       __restrict__ ws_d2,    // [KNN_FQ][kPts]
                int*         __restrict__ ws_f)     // [KNN_FQ][kPts]
{
    __shared__ float4 s_A[kPairs];                         // {cx2, cy2}  20000 B
    __shared__ float4 s_B[kPairs];                         // {cz2, cc2}  20000 B
    __shared__ float  s_best [KNN_WAVES][kPtsPerBlock];    //  8192 B
    __shared__ int    s_bestf[KNN_WAVES][kPtsPerBlock];    //  8192 B

    const int tid  = threadIdx.x;
    const int lane = tid & 63;
    const int wv   = __builtin_amdgcn_readfirstlane(tid >> 6);   // 0..15
    const int pg   = blockIdx.x >> 2;   // point group 0..127
    const int fq   = blockIdx.x & 3;    // face quarter 0..3
    const int qbeg = fq * kQuarter;

    // ---- stage quarter as pair-interleaved SoA (coalesced v2f loads) ----
    for (int p = tid; p < kPairs; p += 1024) {
        const v2f cx2 = *reinterpret_cast<const v2f*>(soa + 0 * kFaces + qbeg + 2 * p);
        const v2f cy2 = *reinterpret_cast<const v2f*>(soa + 1 * kFaces + qbeg + 2 * p);
        const v2f cz2 = *reinterpret_cast<const v2f*>(soa + 2 * kFaces + qbeg + 2 * p);
        const v2f cc2 = *reinterpret_cast<const v2f*>(soa + 3 * kFaces + qbeg + 2 * p);
        s_A[p] = make_float4(cx2.x, cx2.y, cy2.x, cy2.y);
        s_B[p] = make_float4(cz2.x, cz2.y, cc2.x, cc2.y);
    }

    // ---- per-lane 2 points: pre-negated doubled coords (exact) + |q|^2,
    //      duplicated into v2f halves and asm-laundered (no remat) ----
    v2f ndx[kPtsPerLane], ndy[kPtsPerLane], ndz[kPtsPerLane], q2p[kPtsPerLane];
#pragma unroll
    for (int k = 0; k < kPtsPerLane; ++k) {
        const int p = pg * kPtsPerBlock + k * 64 + lane;
        const float qx = verts[p * 3 + 0];
        const float qy = verts[p * 3 + 1];
        const float qz = verts[p * 3 + 2];
        const float q2 = __fadd_rn(__fadd_rn(__fmul_rn(qx, qx), __fmul_rn(qy, qy)),
                                   __fmul_rn(qz, qz));
        const float nx = -__fmul_rn(2.0f, qx);
        const float ny = -__fmul_rn(2.0f, qy);
        const float nz = -__fmul_rn(2.0f, qz);
        ndx[k] = (v2f){nx, nx};  asm("" : "+v"(ndx[k]));
        ndy[k] = (v2f){ny, ny};  asm("" : "+v"(ndy[k]));
        ndz[k] = (v2f){nz, nz};  asm("" : "+v"(ndz[k]));
        q2p[k] = (v2f){q2, q2};  asm("" : "+v"(q2p[k]));
    }

    float bd0[kPtsPerLane], bd1[kPtsPerLane];
    int   bf0[kPtsPerLane], bf1[kPtsPerLane];
#pragma unroll
    for (int k = 0; k < kPtsPerLane; ++k) {
        bd0[k] = INFINITY;   bd1[k] = INFINITY;
        bf0[k] = 0x7fffffff; bf1[k] = 0x7fffffff;
    }

    __syncthreads();

    // this wave's contiguous pair slice (pair-granular; all pairs covered)
    const int pbeg = (wv * kPairs) / KNN_WAVES;
    const int pend = ((wv + 1) * kPairs) / KNN_WAVES;

#pragma unroll 2
    for (int f = pbeg; f < pend; ++f) {
        // 2 x ds_read_b128 at wave-uniform addr (s_A / s_B share a vaddr
        // via LDS offset immediates)
        const float4 ab = s_A[f];
        const float4 zb = s_B[f];
        const v2f cx2 = (v2f){ab.x, ab.y};
        const v2f cy2 = (v2f){ab.z, ab.w};
        const v2f cz2 = (v2f){zb.x, zb.y};
        const v2f cc2 = (v2f){zb.z, zb.w};
        const int gf  = qbeg + 2 * f;
#pragma unroll
        for (int k = 0; k < kPtsPerLane; ++k) {
            // d2 = (q2 + cw) + (-(2q.c)); per-half identical to scalar chain
            const v2f m0   = pk_mul(ndx[k], cx2);
            const v2f m1   = pk_mul(ndy[k], cy2);
            const v2f m2   = pk_mul(ndz[k], cz2);
            const v2f s01  = pk_add(m0, m1);
            const v2f dotn = pk_add(s01, m2);
            const v2f qc   = pk_add(q2p[k], cc2);
            const v2f d2   = pk_add(qc, dotn);
            if (d2.x < bd0[k]) { bd0[k] = d2.x; bf0[k] = gf; }
            if (d2.y < bd1[k]) { bd1[k] = d2.y; bf1[k] = gf + 1; }
        }
    }

    // per-point lexicographic merge of the 2 accumulators (smaller f on ties)
#pragma unroll
    for (int k = 0; k < kPtsPerLane; ++k) {
        if (bd1[k] < bd0[k] || (bd1[k] == bd0[k] && bf1[k] < bf0[k])) {
            bd0[k] = bd1[k]; bf0[k] = bf1[k];
        }
        s_best [wv][k * 64 + lane] = bd0[k];
        s_bestf[wv][k * 64 + lane] = bf0[k];
    }
    __syncthreads();

    // cross-wave merge: fully lexicographic -> partition-independent
    // first-occurrence argmin
    if (tid < kPtsPerBlock) {
        float best  = s_best [0][tid];
        int   bestf = s_bestf[0][tid];
#pragma unroll
        for (int w = 1; w < KNN_WAVES; ++w) {
            const float ob = s_best [w][tid];
            const int   of = s_bestf[w][tid];
            if (ob < best || (ob == best && of < bestf)) { best = ob; bestf = of; }
        }
        const int p = pg * kPtsPerBlock + tid;
        ws_d2[fq * kPts + p] = best;
        ws_f [fq * kPts + p] = bestf;
    }
}

// ---------------------------------------------------------------------------
// quad_perm DPP broadcast: all lanes of each 4-lane quad read lane K.
// ---------------------------------------------------------------------------
template<int K>
__device__ __forceinline__ float qbcast(float v) {
    return __int_as_float(__builtin_amdgcn_update_dpp(
        0, __float_as_int(v), K * 0x55 /*quad_perm[K,K,K,K]*/, 0xF, 0xF, true));
}

// ---------------------------------------------------------------------------
// Kernel 2: solve — UNCHANGED from round 4 (4 lanes per point, one Adam
// channel per lane, DPP quad broadcasts).
// ---------------------------------------------------------------------------
__global__ __launch_bounds__(256)
void solve_kernel(const float* __restrict__ verts,
                  const float* __restrict__ mesh_V,
                  const float* __restrict__ mesh_N,
                  const int*   __restrict__ mesh_F,
                  const float* __restrict__ ws_d2,
                  const int*   __restrict__ ws_f,
                  float*       __restrict__ out)
{
    const int t  = blockIdx.x * 256 + threadIdx.x;
    const int p  = t >> 2;          // point index
    const int ch = t & 3;           // 0=u, 1=v, 2=d, 3=d-duplicate
    const bool isV = (ch == 1);
    const bool isD = (ch >= 2);

    // merge quarters: strict < keeps the earlier quarter on exact ties
    float bdm = ws_d2[p];
    int   f   = ws_f[p];
#pragma unroll
    for (int q = 1; q < KNN_FQ; ++q) {
        const float d  = ws_d2[q * kPts + p];
        const int   ff = ws_f [q * kPts + p];
        if (d < bdm) { bdm = d; f = ff; }
    }
    if (ch == 0) out[p] = (float)f;   // fidx as float (exact for idx < 2^24)

    const float qx = verts[p * 3 + 0];
    const float qy = verts[p * 3 + 1];
    const float qz = verts[p * 3 + 2];

    const int i0 = mesh_F[f * 3 + 0];
    const int i1 = mesh_F[f * 3 + 1];
    const int i2 = mesh_F[f * 3 + 2];

    const float V0x = mesh_V[i0*3+0], V0y = mesh_V[i0*3+1], V0z = mesh_V[i0*3+2];
    const float V1x = mesh_V[i1*3+0], V1y = mesh_V[i1*3+1], V1z = mesh_V[i1*3+2];
    const float V2x = mesh_V[i2*3+0], V2y = mesh_V[i2*3+1], V2z = mesh_V[i2*3+2];
    const float N0x = mesh_N[i0*3+0], N0y = mesh_N[i0*3+1], N0z = mesh_N[i0*3+2];
    const float N1x = mesh_N[i1*3+0], N1y = mesh_N[i1*3+1], N1z = mesh_N[i1*3+2];
    const float N2x = mesh_N[i2*3+0], N2y = mesh_N[i2*3+1], N2z = mesh_N[i2*3+2];

    // edge vectors (same formulas as before)
    const float E0x = V0x - V2x, E0y = V0y - V2y, E0z = V0z - V2z;
    const float E1x = V1x - V2x, E1y = V1y - V2y, E1z = V1z - V2z;
    const float F0x = N0x - N2x, F0y = N0y - N2y, F0z = N0z - N2z;
    const float F1x = N1x - N2x, F1y = N1y - N2y, F1z = N1z - N2z;

    // per-lane operand selects (loop-invariant parts)
    const float Aux = isV ? E1x : E0x;   // A when !isD (the isD case is nh, per-iter)
    const float Auy = isV ? E1y : E0y;
    const float Auz = isV ? E1z : E0z;
    const float Bx  = isD ? 0.0f : (isV ? F1x : F0x);
    const float By  = isD ? 0.0f : (isV ? F1y : F0y);
    const float Bz  = isD ? 0.0f : (isV ? F1z : F0z);

    const float tx = qx * SCALE, ty = qy * SCALE, tz = qz * SCALE;
    const float GS = 2.0f / (3.0f * 16384.0f);
    const float B1c = 0.9f,  ONE_M_B1 = 1.0f - 0.9f;
    const float B2c = 0.999f, ONE_M_B2 = 1.0f - 0.999f;

    float vwu = 1.0f / 3.0f, vwv = 1.0f / 3.0f;

#define SOLVE_STEP(RB1, RB2)                                                   \
    {                                                                          \
        const float du = qbcast<0>(dlt);                                       \
        const float dv = qbcast<1>(dlt);                                       \
        const float dd = qbcast<2>(dlt);                                       \
        const float bu = vwu + du;                                             \
        const float bv = vwv + dv;                                             \
        const float bw = (1.0f - bu) - bv;                                     \
        const float cVx = ((bu * V0x + bv * V1x) + bw * V2x) * SCALE;          \
        const float cVy = ((bu * V0y + bv * V1y) + bw * V2y) * SCALE;          \
        const float cVz = ((bu * V0z + bv * V1z) + bw * V2z) * SCALE;          \
        const float nrx = (bu * N0x + bv * N1x) + bw * N2x;                    \
        const float nry = (bu * N0y + bv * N1y) + bw * N2y;                    \
        const float nrz = (bu * N0z + bv * N1z) + bw * N2z;                    \
        const float nn  = (nrx * nrx + nry * nry) + nrz * nrz;                 \
        const float inv = __builtin_amdgcn_rsqf(nn);                           \
        const float nhx = nrx * inv, nhy = nry * inv, nhz = nrz * inv;         \
        const float cNx = nhx * SCALE, cNy = nhy * SCALE, cNz = nhz * SCALE;   \
        const float rx = (cVx + cNx * dd) - tx;                                \
        const float ry = (cVy + cNy * dd) - ty;                                \
        const float rz = (cVz + cNz * dd) - tz;                                \
        const float Ax = isD ? nhx : Aux;                                      \
        const float Ay = isD ? nhy : Auy;                                      \
        const float Az = isD ? nhz : Auz;                                      \
        const float dotA = (rx * Ax + ry * Ay) + rz * Az;                      \
        const float dotB = (rx * Bx + ry * By) + rz * Bz;                      \
        const float nhB  = (nhx * Bx + nhy * By) + nhz * Bz;                   \
        const float nr_r = qbcast<2>(dotA);                                    \
        const float g = GS * (SCALE * dotA + (dd * SCALE) * ((dotB - nr_r * nhB) * inv)); \
        mA = B1c * mA + ONE_M_B1 * g;                                          \
        vA = B2c * vA + ONE_M_B2 * (g * g);                                    \
        const float s = __builtin_amdgcn_rsqf(vA * (RB2) + 1e-16f);            \
        dlt -= 0.01f * (mA * (RB1)) * s;                                       \
    }

    for (int outer = 0; outer < kOuter; ++outer) {
        const float bw0 = (1.0f - vwu) - vwv;
        const float px = ((vwu * V0x + vwv * V1x) + bw0 * V2x);
        const float py = ((vwu * V0y + vwv * V1y) + bw0 * V2y);
        const float pz = ((vwu * V0z + vwv * V1z) + bw0 * V2z);
        const float dx = px - qx, dy = py - qy, dz = pz - qz;
        const float d0 = __builtin_amdgcn_sqrtf((dx * dx + dy * dy) + dz * dz);

        float dlt = isD ? d0 : 0.0f;   // this lane's channel delta
        float mA  = 0.0f, vA = 0.0f;

        float rbA1 = kTabP.rb[0][0], rbA2 = kTabP.rb[0][1];
        float rbB1 = kTabP.rb[1][0], rbB2 = kTabP.rb[1][1];
#pragma unroll 1
        for (int it2 = 0; it2 < kInner / 2; ++it2) {
            const float n1a = kTabP.rb[2 * it2 + 2][0];
            const float n2a = kTabP.rb[2 * it2 + 2][1];
            const float n1b = kTabP.rb[2 * it2 + 3][0];
            const float n2b = kTabP.rb[2 * it2 + 3][1];
            SOLVE_STEP(rbA1, rbA2);
            SOLVE_STEP(rbB1, rbB2);
            rbA1 = n1a; rbA2 = n2a; rbB1 = n1b; rbB2 = n2b;
        }
        vwu += qbcast<0>(dlt);
        vwv += qbcast<1>(dlt);
    }
#undef SOLVE_STEP

    if (ch == 0) {
        out[kPts + 2 * p + 0] = vwu;
        out[kPts + 2 * p + 1] = vwv;
        out[3 * kPts + p]     = 0.0f;   // outlier_mask = False
    }
}

extern "C" void kernel_launch(void* const* d_in, const int* in_sizes, int n_in,
                              void* d_out, int out_size, void* d_ws, size_t ws_size,
                              hipStream_t stream) {
    const float* verts  = (const float*)d_in[0];
    const float* mesh_V = (const float*)d_in[1];
    const float* mesh_N = (const float*)d_in[2];
    const int*   mesh_F = (const int*)d_in[3];
    float* out = (float*)d_out;

    // workspace layout: SoA centers [4][kFaces] | d2 cand [4][kPts] | f cand
    float* ws_soa = (float*)d_ws;                                           // 160000 B
    float* ws_d2  = (float*)((char*)d_ws + 4 * kFaces * sizeof(float));     // KNN_FQ*kPts floats
    int*   ws_f   = (int*)((char*)ws_d2 + KNN_FQ * kPts * sizeof(float));   // KNN_FQ*kPts ints

    hipLaunchKernelGGL(centers_kernel, dim3((kFaces + 255) / 256), dim3(256), 0, stream,
                       mesh_V, mesh_F, ws_soa);
    hipLaunchKernelGGL(knn_kernel,     dim3(kPtGroups * KNN_FQ), dim3(1024), 0, stream,
                       verts, ws_soa, ws_d2, ws_f);
    hipLaunchKernelGGL(solve_kernel,   dim3(kPts * 4 / 256), dim3(256), 0, stream,
                       verts, mesh_V, mesh_N, mesh_F, ws_d2, ws_f, out);
}

// Round 7
// 124.495 us; speedup vs baseline: 1.0447x; 1.0284x over previous
//
#include <hip/hip_runtime.h>
#include <math.h>
#include <stdint.h>

// Problem constants (match reference)
constexpr int kVerts = 5000;
constexpr int kFaces = 10000;
constexpr int kPts   = 16384;   // BATCH * N_PTS = 2 * 8192
constexpr int kOuter = 4;
constexpr int kInner = 50;

#define SCALE 10.0f

// KNN structure: 4 points per lane, 16 waves per block, 8 face eighths.
// Grid = 64 point-groups x 8 eighths = 512 blocks (2 blocks/CU, 32 waves/CU).
// points-per-wave = 256 -> LDS broadcast traffic halves vs rounds 3-6.
#define KNN_WAVES 16
#define KNN_SEG   8
constexpr int kEighth      = kFaces / KNN_SEG;       // 1250
constexpr int kPairsE      = kEighth / 2;            // 625
constexpr int kPtsPerLane  = 4;
constexpr int kPtsPerBlock = 64 * kPtsPerLane;       // 256
constexpr int kPtGroups    = kPts / kPtsPerBlock;    // 64

typedef float v2f __attribute__((ext_vector_type(2)));

// ---------------------------------------------------------------------------
// Adam bias-correction table (same constexpr values as all prior rounds).
// ---------------------------------------------------------------------------
struct BiasTabP { float rb[kInner + 2][2]; };
constexpr BiasTabP make_tabp() {
    BiasTabP t{};
    float b1 = 1.0f, b2 = 1.0f;
    for (int i = 0; i < kInner; ++i) {
        b1 *= 0.9f; b2 *= 0.999f;
        t.rb[i][0] = 1.0f / (1.0f - b1);
        t.rb[i][1] = 1.0f / (1.0f - b2);
    }
    t.rb[kInner][0]     = t.rb[kInner - 1][0];
    t.rb[kInner][1]     = t.rb[kInner - 1][1];
    t.rb[kInner + 1][0] = t.rb[kInner - 1][0];
    t.rb[kInner + 1][1] = t.rb[kInner - 1][1];
    return t;
}
constexpr BiasTabP kTabP = make_tabp();

// ---------------------------------------------------------------------------
// Kernel 0: triangle centers, SoA output (cx | cy | cz | cc arrays), same
// bit-identical *_rn formulas as every prior round.
// ---------------------------------------------------------------------------
__global__ __launch_bounds__(256)
void centers_kernel(const float* __restrict__ mesh_V,
                    const int*   __restrict__ mesh_F,
                    float*       __restrict__ soa)   // [4][kFaces]
{
    const int f = blockIdx.x * 256 + threadIdx.x;
    if (f >= kFaces) return;
    const int i0 = mesh_F[f * 3 + 0];
    const int i1 = mesh_F[f * 3 + 1];
    const int i2 = mesh_F[f * 3 + 2];
    const float cx = __fdiv_rn(__fadd_rn(__fadd_rn(mesh_V[i0*3+0], mesh_V[i1*3+0]), mesh_V[i2*3+0]), 3.0f);
    const float cy = __fdiv_rn(__fadd_rn(__fadd_rn(mesh_V[i0*3+1], mesh_V[i1*3+1]), mesh_V[i2*3+1]), 3.0f);
    const float cz = __fdiv_rn(__fadd_rn(__fadd_rn(mesh_V[i0*3+2], mesh_V[i1*3+2]), mesh_V[i2*3+2]), 3.0f);
    const float cc = __fadd_rn(__fadd_rn(__fmul_rn(cx, cx), __fmul_rn(cy, cy)),
                               __fmul_rn(cz, cz));
    soa[0 * kFaces + f] = cx;
    soa[1 * kFaces + f] = cy;
    soa[2 * kFaces + f] = cz;
    soa[3 * kFaces + f] = cc;
}

// ---------------------------------------------------------------------------
// Kernel 1: KNN (K=1).
// Round-11. Counter-derived facts from rounds 5/6:
//  - inline-asm pk ops cost ~1.5 forced copies each (54 insts/pair measured
//    vs 32 designed; VGPR squeezed to 24) -> use PLAIN v2f operators; LLVM
//    selects v_pk_mul_f32/v_pk_add_f32 on gfx90a+ with allocator freedom.
//    `#pragma clang fp contract(off)` keeps mul/add unfused (per-half bits
//    == the __fmul_rn/__fadd_rn chain).
//  - LDS broadcast traffic = 16B/face PER WAVE; at 128 pts/wave that is
//    5000 reads/CU ~ 25us, the structural floor of rounds 3-6. 4 pts/lane
//    (256 pts/wave) + FQ=8 keeps 2 blocks/CU and halves it (~12.5us).
//  - q2 dropped from the scan: argmin_f[(q2+cc)-dot] == argmin_f[cc-dot]
//    (per-point additive constant; all per-point merges compare the same
//    s-values). Saves 1 pk + 8 splat VGPRs.
// Eval: 6 pk + 6 select per pair per point = 6 insts/eval (VALU ~12.5us).
// Tie semantics: even->acc0/odd->acc1, all merges lexicographic (s, f) =>
// partition-independent first-occurrence argmin.
// LDS: 20000 (pairs) + 32768 (merge) = 52768 B; 2 blocks/CU fits.
// ---------------------------------------------------------------------------
__global__ __launch_bounds__(1024, 8)
void knn_kernel(const float* __restrict__ verts,
                const float* __restrict__ soa,      // [4][kFaces]
                float*       __restrict__ ws_d2,    // [KNN_SEG][kPts]
                int*         __restrict__ ws_f)     // [KNN_SEG][kPts]
{
    __shared__ float4 s_A[kPairsE];                        // {cx2, cy2}  10000 B
    __shared__ float4 s_B[kPairsE];                        // {cz2, cc2}  10000 B
    __shared__ float  s_best [KNN_WAVES][kPtsPerBlock];    // 16384 B
    __shared__ int    s_bestf[KNN_WAVES][kPtsPerBlock];    // 16384 B

    const int tid  = threadIdx.x;
    const int lane = tid & 63;
    const int wv   = __builtin_amdgcn_readfirstlane(tid >> 6);   // 0..15
    const int pg   = blockIdx.x >> 3;   // point group 0..63
    const int fq   = blockIdx.x & 7;    // face eighth 0..7
    const int qbeg = fq * kEighth;

    // ---- stage eighth as pair-interleaved SoA (coalesced v2f loads) ----
    for (int p = tid; p < kPairsE; p += 1024) {
        const v2f cx2 = *reinterpret_cast<const v2f*>(soa + 0 * kFaces + qbeg + 2 * p);
        const v2f cy2 = *reinterpret_cast<const v2f*>(soa + 1 * kFaces + qbeg + 2 * p);
        const v2f cz2 = *reinterpret_cast<const v2f*>(soa + 2 * kFaces + qbeg + 2 * p);
        const v2f cc2 = *reinterpret_cast<const v2f*>(soa + 3 * kFaces + qbeg + 2 * p);
        s_A[p] = make_float4(cx2.x, cx2.y, cy2.x, cy2.y);
        s_B[p] = make_float4(cz2.x, cz2.y, cc2.x, cc2.y);
    }

    // ---- per-lane 4 points: pre-negated doubled coords (exact), splatted
    //      into v2f halves and laundered ONCE (loop-invariant, no remat) ----
    v2f ndx[kPtsPerLane], ndy[kPtsPerLane], ndz[kPtsPerLane];
#pragma unroll
    for (int k = 0; k < kPtsPerLane; ++k) {
        const int p = pg * kPtsPerBlock + k * 64 + lane;
        const float qx = verts[p * 3 + 0];
        const float qy = verts[p * 3 + 1];
        const float qz = verts[p * 3 + 2];
        const float nx = -__fmul_rn(2.0f, qx);
        const float ny = -__fmul_rn(2.0f, qy);
        const float nz = -__fmul_rn(2.0f, qz);
        ndx[k] = (v2f){nx, nx};  asm("" : "+v"(ndx[k]));
        ndy[k] = (v2f){ny, ny};  asm("" : "+v"(ndy[k]));
        ndz[k] = (v2f){nz, nz};  asm("" : "+v"(ndz[k]));
    }

    float bd0[kPtsPerLane], bd1[kPtsPerLane];
    int   bf0[kPtsPerLane], bf1[kPtsPerLane];
#pragma unroll
    for (int k = 0; k < kPtsPerLane; ++k) {
        bd0[k] = INFINITY;   bd1[k] = INFINITY;
        bf0[k] = 0x7fffffff; bf1[k] = 0x7fffffff;
    }

    __syncthreads();

    // this wave's contiguous pair slice
    const int pbeg = (wv * kPairsE) / KNN_WAVES;
    const int pend = ((wv + 1) * kPairsE) / KNN_WAVES;

#pragma unroll 2
    for (int f = pbeg; f < pend; ++f) {
        // 2 x ds_read_b128 at wave-uniform address (broadcast, in-order)
        const float4 ab = s_A[f];
        const float4 zb = s_B[f];
        const v2f cx2 = (v2f){ab.x, ab.y};
        const v2f cy2 = (v2f){ab.z, ab.w};
        const v2f cz2 = (v2f){zb.x, zb.y};
        const v2f cc2 = (v2f){zb.z, zb.w};
        const int gf  = qbeg + 2 * f;
#pragma unroll
        for (int k = 0; k < kPtsPerLane; ++k) {
            // s = cc + (-(2q.c))  (q2 dropped: per-point additive constant)
            // plain v2f ops -> v_pk_mul_f32 / v_pk_add_f32, per-half IEEE
            // identical to the scalar chain; contraction disabled.
#pragma clang fp contract(off)
            const v2f m0   = ndx[k] * cx2;
            const v2f m1   = ndy[k] * cy2;
            const v2f m2   = ndz[k] * cz2;
            const v2f s01  = m0 + m1;
            const v2f dotn = s01 + m2;
            const v2f sv   = cc2 + dotn;
            if (sv.x < bd0[k]) { bd0[k] = sv.x; bf0[k] = gf; }
            if (sv.y < bd1[k]) { bd1[k] = sv.y; bf1[k] = gf + 1; }
        }
    }

    // per-point lexicographic merge of the 2 accumulators (smaller f on ties)
#pragma unroll
    for (int k = 0; k < kPtsPerLane; ++k) {
        if (bd1[k] < bd0[k] || (bd1[k] == bd0[k] && bf1[k] < bf0[k])) {
            bd0[k] = bd1[k]; bf0[k] = bf1[k];
        }
        s_best [wv][k * 64 + lane] = bd0[k];
        s_bestf[wv][k * 64 + lane] = bf0[k];
    }
    __syncthreads();

    // cross-wave merge: fully lexicographic -> partition-independent
    if (tid < kPtsPerBlock) {
        float best  = s_best [0][tid];
        int   bestf = s_bestf[0][tid];
#pragma unroll
        for (int w = 1; w < KNN_WAVES; ++w) {
            const float ob = s_best [w][tid];
            const int   of = s_bestf[w][tid];
            if (ob < best || (ob == best && of < bestf)) { best = ob; bestf = of; }
        }
        const int p = pg * kPtsPerBlock + tid;
        ws_d2[fq * kPts + p] = best;
        ws_f [fq * kPts + p] = bestf;
    }
}

// ---------------------------------------------------------------------------
// quad_perm DPP broadcast: all lanes of each 4-lane quad read lane K.
// ---------------------------------------------------------------------------
template<int K>
__device__ __forceinline__ float qbcast(float v) {
    return __int_as_float(__builtin_amdgcn_update_dpp(
        0, __float_as_int(v), K * 0x55 /*quad_perm[K,K,K,K]*/, 0xF, 0xF, true));
}

// ---------------------------------------------------------------------------
// Kernel 2: solve — UNCHANGED math (4 lanes/point, one Adam channel per
// lane, DPP quad broadcasts). Only the candidate merge is now 8-way.
// ---------------------------------------------------------------------------
__global__ __launch_bounds__(256)
void solve_kernel(const float* __restrict__ verts,
                  const float* __restrict__ mesh_V,
                  const float* __restrict__ mesh_N,
                  const int*   __restrict__ mesh_F,
                  const float* __restrict__ ws_d2,
                  const int*   __restrict__ ws_f,
                  float*       __restrict__ out)
{
    const int t  = blockIdx.x * 256 + threadIdx.x;
    const int p  = t >> 2;          // point index
    const int ch = t & 3;           // 0=u, 1=v, 2=d, 3=d-duplicate
    const bool isV = (ch == 1);
    const bool isD = (ch >= 2);

    // merge eighths: ascending segment order + strict < keeps smaller f on
    // exact ties == first-occurrence argmin
    float bdm = ws_d2[p];
    int   f   = ws_f[p];
#pragma unroll
    for (int q = 1; q < KNN_SEG; ++q) {
        const float d  = ws_d2[q * kPts + p];
        const int   ff = ws_f [q * kPts + p];
        if (d < bdm) { bdm = d; f = ff; }
    }
    if (ch == 0) out[p] = (float)f;   // fidx as float (exact for idx < 2^24)

    const float qx = verts[p * 3 + 0];
    const float qy = verts[p * 3 + 1];
    const float qz = verts[p * 3 + 2];

    const int i0 = mesh_F[f * 3 + 0];
    const int i1 = mesh_F[f * 3 + 1];
    const int i2 = mesh_F[f * 3 + 2];

    const float V0x = mesh_V[i0*3+0], V0y = mesh_V[i0*3+1], V0z = mesh_V[i0*3+2];
    const float V1x = mesh_V[i1*3+0], V1y = mesh_V[i1*3+1], V1z = mesh_V[i1*3+2];
    const float V2x = mesh_V[i2*3+0], V2y = mesh_V[i2*3+1], V2z = mesh_V[i2*3+2];
    const float N0x = mesh_N[i0*3+0], N0y = mesh_N[i0*3+1], N0z = mesh_N[i0*3+2];
    const float N1x = mesh_N[i1*3+0], N1y = mesh_N[i1*3+1], N1z = mesh_N[i1*3+2];
    const float N2x = mesh_N[i2*3+0], N2y = mesh_N[i2*3+1], N2z = mesh_N[i2*3+2];

    // edge vectors (same formulas as before)
    const float E0x = V0x - V2x, E0y = V0y - V2y, E0z = V0z - V2z;
    const float E1x = V1x - V2x, E1y = V1y - V2y, E1z = V1z - V2z;
    const float F0x = N0x - N2x, F0y = N0y - N2y, F0z = N0z - N2z;
    const float F1x = N1x - N2x, F1y = N1y - N2y, F1z = N1z - N2z;

    // per-lane operand selects (loop-invariant parts)
    const float Aux = isV ? E1x : E0x;   // A when !isD (the isD case is nh, per-iter)
    const float Auy = isV ? E1y : E0y;
    const float Auz = isV ? E1z : E0z;
    const float Bx  = isD ? 0.0f : (isV ? F1x : F0x);
    const float By  = isD ? 0.0f : (isV ? F1y : F0y);
    const float Bz  = isD ? 0.0f : (isV ? F1z : F0z);

    const float tx = qx * SCALE, ty = qy * SCALE, tz = qz * SCALE;
    const float GS = 2.0f / (3.0f * 16384.0f);
    const float B1c = 0.9f,  ONE_M_B1 = 1.0f - 0.9f;
    const float B2c = 0.999f, ONE_M_B2 = 1.0f - 0.999f;

    float vwu = 1.0f / 3.0f, vwv = 1.0f / 3.0f;

#define SOLVE_STEP(RB1, RB2)                                                   \
    {                                                                          \
        const float du = qbcast<0>(dlt);                                       \
        const float dv = qbcast<1>(dlt);                                       \
        const float dd = qbcast<2>(dlt);                                       \
        const float bu = vwu + du;                                             \
        const float bv = vwv + dv;                                             \
        const float bw = (1.0f - bu) - bv;                                     \
        const float cVx = ((bu * V0x + bv * V1x) + bw * V2x) * SCALE;          \
        const float cVy = ((bu * V0y + bv * V1y) + bw * V2y) * SCALE;          \
        const float cVz = ((bu * V0z + bv * V1z) + bw * V2z) * SCALE;          \
        const float nrx = (bu * N0x + bv * N1x) + bw * N2x;                    \
        const float nry = (bu * N0y + bv * N1y) + bw * N2y;                    \
        const float nrz = (bu * N0z + bv * N1z) + bw * N2z;                    \
        const float nn  = (nrx * nrx + nry * nry) + nrz * nrz;                 \
        const float inv = __builtin_amdgcn_rsqf(nn);                           \
        const float nhx = nrx * inv, nhy = nry * inv, nhz = nrz * inv;         \
        const float cNx = nhx * SCALE, cNy = nhy * SCALE, cNz = nhz * SCALE;   \
        const float rx = (cVx + cNx * dd) - tx;                                \
        const float ry = (cVy + cNy * dd) - ty;                                \
        const float rz = (cVz + cNz * dd) - tz;                                \
        const float Ax = isD ? nhx : Aux;                                      \
        const float Ay = isD ? nhy : Auy;                                      \
        const float Az = isD ? nhz : Auz;                                      \
        const float dotA = (rx * Ax + ry * Ay) + rz * Az;                      \
        const float dotB = (rx * Bx + ry * By) + rz * Bz;                      \
        const float nhB  = (nhx * Bx + nhy * By) + nhz * Bz;                   \
        const float nr_r = qbcast<2>(dotA);                                    \
        const float g = GS * (SCALE * dotA + (dd * SCALE) * ((dotB - nr_r * nhB) * inv)); \
        mA = B1c * mA + ONE_M_B1 * g;                                          \
        vA = B2c * vA + ONE_M_B2 * (g * g);                                    \
        const float s = __builtin_amdgcn_rsqf(vA * (RB2) + 1e-16f);            \
        dlt -= 0.01f * (mA * (RB1)) * s;                                       \
    }

    for (int outer = 0; outer < kOuter; ++outer) {
        const float bw0 = (1.0f - vwu) - vwv;
        const float px = ((vwu * V0x + vwv * V1x) + bw0 * V2x);
        const float py = ((vwu * V0y + vwv * V1y) + bw0 * V2y);
        const float pz = ((vwu * V0z + vwv * V1z) + bw0 * V2z);
        const float dx = px - qx, dy = py - qy, dz = pz - qz;
        const float d0 = __builtin_amdgcn_sqrtf((dx * dx + dy * dy) + dz * dz);

        float dlt = isD ? d0 : 0.0f;   // this lane's channel delta
        float mA  = 0.0f, vA = 0.0f;

        float rbA1 = kTabP.rb[0][0], rbA2 = kTabP.rb[0][1];
        float rbB1 = kTabP.rb[1][0], rbB2 = kTabP.rb[1][1];
#pragma unroll 1
        for (int it2 = 0; it2 < kInner / 2; ++it2) {
            const float n1a = kTabP.rb[2 * it2 + 2][0];
            const float n2a = kTabP.rb[2 * it2 + 2][1];
            const float n1b = kTabP.rb[2 * it2 + 3][0];
            const float n2b = kTabP.rb[2 * it2 + 3][1];
            SOLVE_STEP(rbA1, rbA2);
            SOLVE_STEP(rbB1, rbB2);
            rbA1 = n1a; rbA2 = n2a; rbB1 = n1b; rbB2 = n2b;
        }
        vwu += qbcast<0>(dlt);
        vwv += qbcast<1>(dlt);
    }
#undef SOLVE_STEP

    if (ch == 0) {
        out[kPts + 2 * p + 0] = vwu;
        out[kPts + 2 * p + 1] = vwv;
        out[3 * kPts + p]     = 0.0f;   // outlier_mask = False
    }
}

extern "C" void kernel_launch(void* const* d_in, const int* in_sizes, int n_in,
                              void* d_out, int out_size, void* d_ws, size_t ws_size,
                              hipStream_t stream) {
    const float* verts  = (const float*)d_in[0];
    const float* mesh_V = (const float*)d_in[1];
    const float* mesh_N = (const float*)d_in[2];
    const int*   mesh_F = (const int*)d_in[3];
    float* out = (float*)d_out;

    // workspace layout: SoA centers [4][kFaces] | d2 cand [8][kPts] | f cand
    float* ws_soa = (float*)d_ws;                                           // 160000 B
    float* ws_d2  = (float*)((char*)d_ws + 4 * kFaces * sizeof(float));     // KNN_SEG*kPts floats
    int*   ws_f   = (int*)((char*)ws_d2 + KNN_SEG * kPts * sizeof(float));  // KNN_SEG*kPts ints

    hipLaunchKernelGGL(centers_kernel, dim3((kFaces + 255) / 256), dim3(256), 0, stream,
                       mesh_V, mesh_F, ws_soa);
    hipLaunchKernelGGL(knn_kernel,     dim3(kPtGroups * KNN_SEG), dim3(1024), 0, stream,
                       verts, ws_soa, ws_d2, ws_f);
    hipLaunchKernelGGL(solve_kernel,   dim3(kPts * 4 / 256), dim3(256), 0, stream,
                       verts, mesh_V, mesh_N, mesh_F, ws_d2, ws_f, out);
}